// Round 2
// baseline (376.082 us; speedup 1.0000x reference)
//
#include <hip/hip_runtime.h>
#include <stdint.h>
#include <math.h>

#define EPSV   1e-5f
#define BATCH  4096
#define GDIM   4096
#define NFEAT  1536   // 64 terms * 24

typedef __attribute__((ext_vector_type(8))) short bf16x8;
typedef __attribute__((ext_vector_type(4))) float f32x4;
typedef __attribute__((ext_vector_type(4))) uint32_t u32x4;

// pack two f32 -> two bf16 (round-half-up) in one dword: low16=bf16(x), high16=bf16(y)
__device__ __forceinline__ uint32_t pkbf(float x, float y) {
    uint32_t a = __float_as_uint(x) + 0x8000u;
    uint32_t b = __float_as_uint(y) + 0x8000u;
    // result bytes (LSB..MSB): a.b2, a.b3, b.b2, b.b3
    return __builtin_amdgcn_perm(b, a, 0x07060302u);
}

// ---------------------------------------------------------------------------
// GEMM: C[M,N] = A[M,K] @ Bw[N,K]^T + bias   (A=x f32, Bw=gene_W f32, f32 out)
// 128x128 tile, BK=32, 4 waves (2x2), each wave 64x64 via 4x4 mfma 16x16x32.
// f32 global loads, convert to bf16 during LDS staging.
// ---------------------------------------------------------------------------
__global__ __launch_bounds__(256) void gemm_bt(
    const float* __restrict__ A, const float* __restrict__ Bw,
    const float* __restrict__ bias, float* __restrict__ C)
{
    const int N = NFEAT, K = GDIM;
    __shared__ short sA[128 * 32];
    __shared__ short sB[128 * 32];
    const int tid  = threadIdx.x;
    const int m0   = blockIdx.y * 128, n0 = blockIdx.x * 128;
    const int wave = tid >> 6, lane = tid & 63;
    const int wm   = (wave & 1) << 6, wn = (wave >> 1) << 6;
    const int lm   = lane & 15, quad = lane >> 4;

    f32x4 acc[4][4];
#pragma unroll
    for (int i = 0; i < 4; ++i)
#pragma unroll
        for (int j = 0; j < 4; ++j) acc[i][j] = (f32x4){0.f, 0.f, 0.f, 0.f};

    // staging: thread t covers 8 bf16 (16 LDS bytes) per row-pass
    const int r0 = tid >> 2;              // row 0..63 (pass 0), +64 (pass 1)
    const int c0 = (tid & 3) << 3;        // elem col 0/8/16/24
    const float* ga = A  + (size_t)(m0 + r0) * K + c0;
    const float* gb = Bw + (size_t)(n0 + r0) * K + c0;
    uint32_t* wa = (uint32_t*)&sA[r0 * 32 + c0];
    uint32_t* wb = (uint32_t*)&sB[r0 * 32 + c0];
    const size_t rowskip = (size_t)64 * K;

    for (int k0 = 0; k0 < K; k0 += 32) {
        f32x4 a00 = *(const f32x4*)(ga + k0);
        f32x4 a01 = *(const f32x4*)(ga + k0 + 4);
        f32x4 a10 = *(const f32x4*)(ga + rowskip + k0);
        f32x4 a11 = *(const f32x4*)(ga + rowskip + k0 + 4);
        f32x4 b00 = *(const f32x4*)(gb + k0);
        f32x4 b01 = *(const f32x4*)(gb + k0 + 4);
        f32x4 b10 = *(const f32x4*)(gb + rowskip + k0);
        f32x4 b11 = *(const f32x4*)(gb + rowskip + k0 + 4);
        u32x4 pa0 = (u32x4){pkbf(a00[0],a00[1]), pkbf(a00[2],a00[3]),
                            pkbf(a01[0],a01[1]), pkbf(a01[2],a01[3])};
        u32x4 pa1 = (u32x4){pkbf(a10[0],a10[1]), pkbf(a10[2],a10[3]),
                            pkbf(a11[0],a11[1]), pkbf(a11[2],a11[3])};
        u32x4 pb0 = (u32x4){pkbf(b00[0],b00[1]), pkbf(b00[2],b00[3]),
                            pkbf(b01[0],b01[1]), pkbf(b01[2],b01[3])};
        u32x4 pb1 = (u32x4){pkbf(b10[0],b10[1]), pkbf(b10[2],b10[3]),
                            pkbf(b11[0],b11[1]), pkbf(b11[2],b11[3])};
        __syncthreads();                       // prev iter frag reads done
        *(u32x4*)wa               = pa0;
        *(u32x4*)(wa + 64*32/2)   = pa1;       // +64 rows (32 shorts = 16 dwords/row)
        *(u32x4*)wb               = pb0;
        *(u32x4*)(wb + 64*32/2)   = pb1;
        __syncthreads();
        bf16x8 af[4], bfr[4];
#pragma unroll
        for (int m = 0; m < 4; ++m)
            af[m]  = *(const bf16x8*)&sA[(wm + m * 16 + lm) * 32 + quad * 8];
#pragma unroll
        for (int n = 0; n < 4; ++n)
            bfr[n] = *(const bf16x8*)&sB[(wn + n * 16 + lm) * 32 + quad * 8];
#pragma unroll
        for (int m = 0; m < 4; ++m)
#pragma unroll
            for (int n = 0; n < 4; ++n)
                acc[m][n] = __builtin_amdgcn_mfma_f32_16x16x32_bf16(
                    af[m], bfr[n], acc[m][n], 0, 0, 0);
    }
    // C/D layout: col = lane&15, row = quad*4 + reg   [m89/m91-verified]
#pragma unroll
    for (int n = 0; n < 4; ++n) {
        const int col = n0 + wn + n * 16 + lm;
        const float bv = bias[col];
#pragma unroll
        for (int m = 0; m < 4; ++m) {
            const int row = m0 + wm + m * 16 + (quad << 2);
            float* cp = C + (size_t)row * N + col;
#pragma unroll
            for (int r = 0; r < 4; ++r) cp[(size_t)r * N] = acc[m][n][r] + bv;
        }
    }
}

// ---------------------------------------------------------------------------
// Level kernel: reads 'in' (B x 24N). If HAS_PREV, 'in' is prev-level z and is
// normalized with (a,c) derived from stats_prev + gamma/beta; prev-level aux
// outputs (4N cols at PREV_OFF) are emitted. Computes z = tanh(in.Wt + b)
// (6 per term), writes z_out, accumulates per-feature sum/sumsq -> stats_out.
// ---------------------------------------------------------------------------
template <int N, int ROWS, bool HAS_PREV, int OFF, int PREV_OFF>
__global__ __launch_bounds__(256) void level_kernel(
    const float* __restrict__ in, float* __restrict__ z_out,
    const float* __restrict__ stats_prev, float* __restrict__ stats_out,
    const float* __restrict__ term_W, const float* __restrict__ term_b,
    const float* __restrict__ bn_gamma, const float* __restrict__ bn_beta,
    const float* __restrict__ aux1_W, const float* __restrict__ aux1_b,
    const float* __restrict__ aux2_W, const float* __restrict__ aux2_b,
    float* __restrict__ out)
{
    constexpr int IN_W  = 24 * N;
    constexpr int NF    = 6 * N;
    constexpr int NG    = 256 / N;
    constexpr int ITERS = (ROWS * N) / 256;
    constexpr int NPREV = HAS_PREV ? 4 * N : 1;

    __shared__ float Wl[144 * N];               // [h*24+i][term]  (term-major: conflict-free)
    __shared__ float tbl[6 * N];                // [h][term]
    __shared__ float aA[HAS_PREV ? IN_W : 1];   // [i][term]
    __shared__ float aC[HAS_PREV ? IN_W : 1];
    __shared__ float a1wL[HAS_PREV ? 6 * NPREV : 1];  // [h][t']
    __shared__ float a1bL[NPREV], a2wL[NPREV], a2bL[NPREV];
    __shared__ float ps[NG * NF], pq[NG * NF];  // 1536 f32 each for every level

    const int tid = threadIdx.x;
    for (int idx = tid; idx < 144 * N; idx += 256) {
        int t = idx / 144, fh = idx - t * 144;
        Wl[fh * N + t] = term_W[(OFF + t) * 144 + fh];
    }
    for (int idx = tid; idx < 6 * N; idx += 256) {
        int t = idx / 6, h = idx - t * 6;
        tbl[h * N + t] = term_b[(OFF + t) * 6 + h];
    }
    if constexpr (HAS_PREV) {
        const float invB = 1.0f / BATCH;
        for (int j = tid; j < IN_W; j += 256) {
            float s = stats_prev[j], q = stats_prev[IN_W + j];
            float mu = s * invB;
            float var = q * invB - mu * mu;
            float rstd = rsqrtf(var + EPSV);
            float a = rstd * bn_gamma[PREV_OFF * 6 + j];
            int t = j / 24, i = j - t * 24;
            aA[i * N + t] = a;
            aC[i * N + t] = bn_beta[PREV_OFF * 6 + j] - mu * a;
        }
        for (int idx = tid; idx < 6 * NPREV; idx += 256) {
            int t = idx / 6, h = idx - t * 6;
            a1wL[h * NPREV + t] = aux1_W[(PREV_OFF + t) * 6 + h];
        }
        for (int t = tid; t < NPREV; t += 256) {
            a1bL[t] = aux1_b[PREV_OFF + t];
            a2wL[t] = aux2_W[PREV_OFF + t];
            a2bL[t] = aux2_b[PREV_OFF + t];
        }
    }
    __syncthreads();

    const int term = tid & (N - 1);
    const int grp  = tid / N;
    float s6[6], q6[6];
#pragma unroll
    for (int h = 0; h < 6; ++h) { s6[h] = 0.f; q6[h] = 0.f; }

    for (int it = 0; it < ITERS; ++it) {
        const int r = blockIdx.x * ROWS + it * NG + grp;
        const float* inrow = in + (size_t)r * IN_W + term * 24;
        float hv[24];
#pragma unroll
        for (int i4 = 0; i4 < 6; ++i4) {
            f32x4 v = *(const f32x4*)(inrow + 4 * i4);
            hv[4*i4+0] = v[0]; hv[4*i4+1] = v[1];
            hv[4*i4+2] = v[2]; hv[4*i4+3] = v[3];
        }
        if constexpr (HAS_PREV) {
#pragma unroll
            for (int i = 0; i < 24; ++i)
                hv[i] = hv[i] * aA[i * N + term] + aC[i * N + term];
            // aux outputs of previous level (4 per cell)
#pragma unroll
            for (int s = 0; s < 4; ++s) {
                const int tp = term * 4 + s;
                float acc = a1bL[tp];
#pragma unroll
                for (int h2 = 0; h2 < 6; ++h2) acc += hv[s * 6 + h2] * a1wL[h2 * NPREV + tp];
                float a1 = tanhf(acc);
                out[(size_t)r * 86 + PREV_OFF + tp] = a1 * a2wL[tp] + a2bL[tp];
            }
        }
        float za[6];
#pragma unroll
        for (int h = 0; h < 6; ++h) za[h] = tbl[h * N + term];
#pragma unroll
        for (int i = 0; i < 24; ++i) {
            const float x = hv[i];
#pragma unroll
            for (int h = 0; h < 6; ++h) za[h] += x * Wl[(h * 24 + i) * N + term];
        }
        float* zr = z_out + (size_t)r * NF + term * 6;
#pragma unroll
        for (int h = 0; h < 6; ++h) {
            float z = tanhf(za[h]);
            zr[h] = z;
            s6[h] += z;
            q6[h] += z * z;
        }
    }
#pragma unroll
    for (int h = 0; h < 6; ++h) {
        ps[grp * NF + term * 6 + h] = s6[h];
        pq[grp * NF + term * 6 + h] = q6[h];
    }
    __syncthreads();
    for (int f = tid; f < NF; f += 256) {
        float s = 0.f, q = 0.f;
        for (int g2 = 0; g2 < NG; ++g2) { s += ps[g2 * NF + f]; q += pq[g2 * NF + f]; }
        atomicAdd(&stats_out[f], s);
        atomicAdd(&stats_out[NF + f], q);
    }
}

// ---------------------------------------------------------------------------
// finalA: normalize z3 (level-3 BN), emit aux col 84, f = tanh(h @ final_W^T + b),
// store f, accumulate fbn stats.
// ---------------------------------------------------------------------------
__global__ __launch_bounds__(256) void final_a_kernel(
    const float* __restrict__ z3, const float* __restrict__ st3,
    float* __restrict__ fbuf, float* __restrict__ stf,
    const float* __restrict__ bn_gamma, const float* __restrict__ bn_beta,
    const float* __restrict__ aux1_W, const float* __restrict__ aux1_b,
    const float* __restrict__ aux2_W, const float* __restrict__ aux2_b,
    const float* __restrict__ final_W, const float* __restrict__ final_b,
    float* __restrict__ out)
{
    __shared__ float sfs[6], sfq[6];
    const int tid = threadIdx.x;
    if (tid < 6) { sfs[tid] = 0.f; sfq[tid] = 0.f; }
    const float invB = 1.0f / BATCH;
    float a[6], c[6];
#pragma unroll
    for (int j = 0; j < 6; ++j) {
        float s = st3[j], q = st3[6 + j];
        float mu = s * invB, var = q * invB - mu * mu;
        float rstd = rsqrtf(var + EPSV);
        a[j] = rstd * bn_gamma[84 * 6 + j];
        c[j] = bn_beta[84 * 6 + j] - mu * a[j];
    }
    __syncthreads();
    const int r = blockIdx.x * 256 + tid;
    float h[6];
#pragma unroll
    for (int j = 0; j < 6; ++j) h[j] = z3[(size_t)r * 6 + j] * a[j] + c[j];
    float acc = aux1_b[84];
#pragma unroll
    for (int j = 0; j < 6; ++j) acc += h[j] * aux1_W[84 * 6 + j];
    float a1 = tanhf(acc);
    out[(size_t)r * 86 + 84] = a1 * aux2_W[84] + aux2_b[84];
    float fv[6];
#pragma unroll
    for (int j = 0; j < 6; ++j) {
        float s = final_b[j];
#pragma unroll
        for (int k = 0; k < 6; ++k) s += h[k] * final_W[j * 6 + k];
        fv[j] = tanhf(s);
        fbuf[(size_t)r * 6 + j] = fv[j];
    }
#pragma unroll
    for (int j = 0; j < 6; ++j) {
        atomicAdd(&sfs[j], fv[j]);
        atomicAdd(&sfq[j], fv[j] * fv[j]);
    }
    __syncthreads();
    if (tid < 6) {
        atomicAdd(&stf[tid], sfs[tid]);
        atomicAdd(&stf[6 + tid], sfq[tid]);
    }
}

// ---------------------------------------------------------------------------
// finalB: fbn-normalize f, fa = tanh(f . faux_W + b), pred = sigmoid(...), col 85
// ---------------------------------------------------------------------------
__global__ __launch_bounds__(256) void final_b_kernel(
    const float* __restrict__ fbuf, const float* __restrict__ stf,
    const float* __restrict__ fbn_gamma, const float* __restrict__ fbn_beta,
    const float* __restrict__ faux_W, const float* __restrict__ faux_b,
    const float* __restrict__ fout_W, const float* __restrict__ fout_b,
    float* __restrict__ out)
{
    const int r = blockIdx.x * 256 + threadIdx.x;
    const float invB = 1.0f / BATCH;
    float acc = faux_b[0];
#pragma unroll
    for (int j = 0; j < 6; ++j) {
        float s = stf[j], q = stf[6 + j];
        float mu = s * invB, var = q * invB - mu * mu;
        float rstd = rsqrtf(var + EPSV);
        float av = rstd * fbn_gamma[j];
        float cv = fbn_beta[j] - mu * av;
        float fn = fbuf[(size_t)r * 6 + j] * av + cv;
        acc += fn * faux_W[j];
    }
    float fa  = tanhf(acc);
    float pre = fa * fout_W[0] + fout_b[0];
    float pred = 1.0f / (1.0f + expf(-pre));
    out[(size_t)r * 86 + 85] = pred;
}

// ---------------------------------------------------------------------------
extern "C" void kernel_launch(void* const* d_in, const int* in_sizes, int n_in,
                              void* d_out, int out_size, void* d_ws, size_t ws_size,
                              hipStream_t stream)
{
    const float* x      = (const float*)d_in[0];
    const float* gene_W = (const float*)d_in[1];
    const float* gene_b = (const float*)d_in[2];
    const float* term_W = (const float*)d_in[3];
    const float* term_b = (const float*)d_in[4];
    const float* bn_g   = (const float*)d_in[5];
    const float* bn_b   = (const float*)d_in[6];
    const float* a1W    = (const float*)d_in[7];
    const float* a1b    = (const float*)d_in[8];
    const float* a2W    = (const float*)d_in[9];
    const float* a2b    = (const float*)d_in[10];
    const float* fW     = (const float*)d_in[11];
    const float* fb     = (const float*)d_in[12];
    const float* fbn_g  = (const float*)d_in[13];
    const float* fbn_b  = (const float*)d_in[14];
    const float* fxW    = (const float*)d_in[15];
    const float* fxb    = (const float*)d_in[16];
    const float* foW    = (const float*)d_in[17];
    const float* fob    = (const float*)d_in[18];
    float* out = (float*)d_out;

    char* ws = (char*)d_ws;
    float* h_in = (float*)(ws);                 // 4096*1536 f32 = 25165824 B
    float* z0   = (float*)(ws + 25165824);      // 4096*384
    float* z1   = (float*)(ws + 31457280);      // 4096*96
    float* z2   = (float*)(ws + 33030144);      // 4096*24
    float* z3   = (float*)(ws + 33423360);      // 4096*6
    float* fbuf = (float*)(ws + 33521664);      // 4096*6
    float* stats = (float*)(ws + 33619968);     // 1032 f32
    float* st0 = stats;         // 384 sum + 384 sq
    float* st1 = stats + 768;   // 96+96
    float* st2 = stats + 960;   // 24+24
    float* st3 = stats + 1008;  // 6+6
    float* stf = stats + 1020;  // 6+6

    hipMemsetAsync(stats, 0, 1032 * sizeof(float), stream);
    gemm_bt<<<dim3(12, 32), 256, 0, stream>>>(x, gene_W, gene_b, h_in);
    level_kernel<64, 16, false, 0, 0><<<256, 256, 0, stream>>>(
        h_in, z0, nullptr, st0, term_W, term_b, bn_g, bn_b, a1W, a1b, a2W, a2b, out);
    level_kernel<16, 16, true, 64, 0><<<256, 256, 0, stream>>>(
        z0, z1, st0, st1, term_W, term_b, bn_g, bn_b, a1W, a1b, a2W, a2b, out);
    level_kernel<4, 64, true, 80, 64><<<64, 256, 0, stream>>>(
        z1, z2, st1, st2, term_W, term_b, bn_g, bn_b, a1W, a1b, a2W, a2b, out);
    level_kernel<1, 256, true, 84, 80><<<16, 256, 0, stream>>>(
        z2, z3, st2, st3, term_W, term_b, bn_g, bn_b, a1W, a1b, a2W, a2b, out);
    final_a_kernel<<<16, 256, 0, stream>>>(
        z3, st3, fbuf, stf, bn_g, bn_b, a1W, a1b, a2W, a2b, fW, fb, out);
    final_b_kernel<<<16, 256, 0, stream>>>(
        fbuf, stf, fbn_g, fbn_b, fxW, fxb, foW, fob, out);
}

// Round 3
// 314.040 us; speedup vs baseline: 1.1976x; 1.1976x over previous
//
#include <hip/hip_runtime.h>
#include <stdint.h>
#include <math.h>

#define EPSV   1e-5f
#define BATCH  4096
#define GDIM   4096
#define NFEAT  1536   // 64 terms * 24

typedef __attribute__((ext_vector_type(8))) short bf16x8;
typedef __attribute__((ext_vector_type(4))) float f32x4;
typedef __attribute__((ext_vector_type(4))) uint32_t u32x4;

// pack two f32 -> two bf16 (round-half-up) in one dword
__device__ __forceinline__ uint32_t pkbf(float x, float y) {
    uint32_t a = __float_as_uint(x) + 0x8000u;
    uint32_t b = __float_as_uint(y) + 0x8000u;
    return __builtin_amdgcn_perm(b, a, 0x07060302u);
}

// ---------------------------------------------------------------------------
// GEMM: C[M,N] = A[M,K] @ Bw[N,K]^T (+bias on split 0)
// 128x128 tile, BK=32, 4 waves (2x2), wave 64x64 via 4x4 mfma 16x16x32.
// Split-K over blockIdx.z: split z covers k in [z*KC, (z+1)*KC), writes
// C + z*BATCH*NFEAT. f32 global loads, bf16 convert during LDS staging.
// ---------------------------------------------------------------------------
__global__ __launch_bounds__(256) void gemm_bt(
    const float* __restrict__ A, const float* __restrict__ Bw,
    const float* __restrict__ bias, float* __restrict__ C, int KC)
{
    const int N = NFEAT, K = GDIM;
    __shared__ short sA[128 * 32];
    __shared__ short sB[128 * 32];
    const int tid  = threadIdx.x;
    const int m0   = blockIdx.y * 128, n0 = blockIdx.x * 128;
    const int kbase = blockIdx.z * KC;
    float* Cp = C + (size_t)blockIdx.z * ((size_t)BATCH * NFEAT);
    const int wave = tid >> 6, lane = tid & 63;
    const int wm   = (wave & 1) << 6, wn = (wave >> 1) << 6;
    const int lm   = lane & 15, quad = lane >> 4;

    f32x4 acc[4][4];
#pragma unroll
    for (int i = 0; i < 4; ++i)
#pragma unroll
        for (int j = 0; j < 4; ++j) acc[i][j] = (f32x4){0.f, 0.f, 0.f, 0.f};

    const int r0 = tid >> 2;              // row 0..63 (pass 0), +64 (pass 1)
    const int c0 = (tid & 3) << 3;        // elem col 0/8/16/24
    const float* ga = A  + (size_t)(m0 + r0) * K + kbase + c0;
    const float* gb = Bw + (size_t)(n0 + r0) * K + kbase + c0;
    uint32_t* wa = (uint32_t*)&sA[r0 * 32 + c0];
    uint32_t* wb = (uint32_t*)&sB[r0 * 32 + c0];
    const size_t rowskip = (size_t)64 * K;

    for (int k0 = 0; k0 < KC; k0 += 32) {
        f32x4 a00 = *(const f32x4*)(ga + k0);
        f32x4 a01 = *(const f32x4*)(ga + k0 + 4);
        f32x4 a10 = *(const f32x4*)(ga + rowskip + k0);
        f32x4 a11 = *(const f32x4*)(ga + rowskip + k0 + 4);
        f32x4 b00 = *(const f32x4*)(gb + k0);
        f32x4 b01 = *(const f32x4*)(gb + k0 + 4);
        f32x4 b10 = *(const f32x4*)(gb + rowskip + k0);
        f32x4 b11 = *(const f32x4*)(gb + rowskip + k0 + 4);
        u32x4 pa0 = (u32x4){pkbf(a00[0],a00[1]), pkbf(a00[2],a00[3]),
                            pkbf(a01[0],a01[1]), pkbf(a01[2],a01[3])};
        u32x4 pa1 = (u32x4){pkbf(a10[0],a10[1]), pkbf(a10[2],a10[3]),
                            pkbf(a11[0],a11[1]), pkbf(a11[2],a11[3])};
        u32x4 pb0 = (u32x4){pkbf(b00[0],b00[1]), pkbf(b00[2],b00[3]),
                            pkbf(b01[0],b01[1]), pkbf(b01[2],b01[3])};
        u32x4 pb1 = (u32x4){pkbf(b10[0],b10[1]), pkbf(b10[2],b10[3]),
                            pkbf(b11[0],b11[1]), pkbf(b11[2],b11[3])};
        __syncthreads();
        *(u32x4*)wa               = pa0;
        *(u32x4*)(wa + 64*32/2)   = pa1;
        *(u32x4*)wb               = pb0;
        *(u32x4*)(wb + 64*32/2)   = pb1;
        __syncthreads();
        bf16x8 af[4], bfr[4];
#pragma unroll
        for (int m = 0; m < 4; ++m)
            af[m]  = *(const bf16x8*)&sA[(wm + m * 16 + lm) * 32 + quad * 8];
#pragma unroll
        for (int n = 0; n < 4; ++n)
            bfr[n] = *(const bf16x8*)&sB[(wn + n * 16 + lm) * 32 + quad * 8];
#pragma unroll
        for (int m = 0; m < 4; ++m)
#pragma unroll
            for (int n = 0; n < 4; ++n)
                acc[m][n] = __builtin_amdgcn_mfma_f32_16x16x32_bf16(
                    af[m], bfr[n], acc[m][n], 0, 0, 0);
    }
#pragma unroll
    for (int n = 0; n < 4; ++n) {
        const int col = n0 + wn + n * 16 + lm;
        const float bv = (blockIdx.z == 0) ? bias[col] : 0.f;
#pragma unroll
        for (int m = 0; m < 4; ++m) {
            const int row = m0 + wm + m * 16 + (quad << 2);
            float* cp = Cp + (size_t)row * N + col;
#pragma unroll
            for (int r = 0; r < 4; ++r) cp[(size_t)r * N] = acc[m][n][r] + bv;
        }
    }
}

// ---------------------------------------------------------------------------
// Level kernel (unchanged structure; optional second input summed in = split-K
// partial). See R1 comments.
// ---------------------------------------------------------------------------
template <int N, int ROWS, bool HAS_PREV, int OFF, int PREV_OFF, bool TWO_IN>
__global__ __launch_bounds__(256) void level_kernel(
    const float* __restrict__ in, const float* __restrict__ in2,
    float* __restrict__ z_out,
    const float* __restrict__ stats_prev, float* __restrict__ stats_out,
    const float* __restrict__ term_W, const float* __restrict__ term_b,
    const float* __restrict__ bn_gamma, const float* __restrict__ bn_beta,
    const float* __restrict__ aux1_W, const float* __restrict__ aux1_b,
    const float* __restrict__ aux2_W, const float* __restrict__ aux2_b,
    float* __restrict__ out)
{
    constexpr int IN_W  = 24 * N;
    constexpr int NF    = 6 * N;
    constexpr int NG    = 256 / N;
    constexpr int ITERS = (ROWS * N) / 256;
    constexpr int NPREV = HAS_PREV ? 4 * N : 1;

    __shared__ float Wl[144 * N];
    __shared__ float tbl[6 * N];
    __shared__ float aA[HAS_PREV ? IN_W : 1];
    __shared__ float aC[HAS_PREV ? IN_W : 1];
    __shared__ float a1wL[HAS_PREV ? 6 * NPREV : 1];
    __shared__ float a1bL[NPREV], a2wL[NPREV], a2bL[NPREV];
    __shared__ float ps[NG * NF], pq[NG * NF];

    const int tid = threadIdx.x;
    for (int idx = tid; idx < 144 * N; idx += 256) {
        int t = idx / 144, fh = idx - t * 144;
        Wl[fh * N + t] = term_W[(OFF + t) * 144 + fh];
    }
    for (int idx = tid; idx < 6 * N; idx += 256) {
        int t = idx / 6, h = idx - t * 6;
        tbl[h * N + t] = term_b[(OFF + t) * 6 + h];
    }
    if constexpr (HAS_PREV) {
        const float invB = 1.0f / BATCH;
        for (int j = tid; j < IN_W; j += 256) {
            float s = stats_prev[j], q = stats_prev[IN_W + j];
            float mu = s * invB;
            float var = q * invB - mu * mu;
            float rstd = rsqrtf(var + EPSV);
            float a = rstd * bn_gamma[PREV_OFF * 6 + j];
            int t = j / 24, i = j - t * 24;
            aA[i * N + t] = a;
            aC[i * N + t] = bn_beta[PREV_OFF * 6 + j] - mu * a;
        }
        for (int idx = tid; idx < 6 * NPREV; idx += 256) {
            int t = idx / 6, h = idx - t * 6;
            a1wL[h * NPREV + t] = aux1_W[(PREV_OFF + t) * 6 + h];
        }
        for (int t = tid; t < NPREV; t += 256) {
            a1bL[t] = aux1_b[PREV_OFF + t];
            a2wL[t] = aux2_W[PREV_OFF + t];
            a2bL[t] = aux2_b[PREV_OFF + t];
        }
    }
    __syncthreads();

    const int term = tid & (N - 1);
    const int grp  = tid / N;
    float s6[6], q6[6];
#pragma unroll
    for (int h = 0; h < 6; ++h) { s6[h] = 0.f; q6[h] = 0.f; }

    for (int it = 0; it < ITERS; ++it) {
        const int r = blockIdx.x * ROWS + it * NG + grp;
        const float* inrow = in + (size_t)r * IN_W + term * 24;
        float hv[24];
#pragma unroll
        for (int i4 = 0; i4 < 6; ++i4) {
            f32x4 v = *(const f32x4*)(inrow + 4 * i4);
            hv[4*i4+0] = v[0]; hv[4*i4+1] = v[1];
            hv[4*i4+2] = v[2]; hv[4*i4+3] = v[3];
        }
        if constexpr (TWO_IN) {
            const float* inrow2 = in2 + (size_t)r * IN_W + term * 24;
#pragma unroll
            for (int i4 = 0; i4 < 6; ++i4) {
                f32x4 v = *(const f32x4*)(inrow2 + 4 * i4);
                hv[4*i4+0] += v[0]; hv[4*i4+1] += v[1];
                hv[4*i4+2] += v[2]; hv[4*i4+3] += v[3];
            }
        }
        if constexpr (HAS_PREV) {
#pragma unroll
            for (int i = 0; i < 24; ++i)
                hv[i] = hv[i] * aA[i * N + term] + aC[i * N + term];
#pragma unroll
            for (int s = 0; s < 4; ++s) {
                const int tp = term * 4 + s;
                float acc = a1bL[tp];
#pragma unroll
                for (int h2 = 0; h2 < 6; ++h2) acc += hv[s * 6 + h2] * a1wL[h2 * NPREV + tp];
                float a1 = tanhf(acc);
                out[(size_t)r * 86 + PREV_OFF + tp] = a1 * a2wL[tp] + a2bL[tp];
            }
        }
        float za[6];
#pragma unroll
        for (int h = 0; h < 6; ++h) za[h] = tbl[h * N + term];
#pragma unroll
        for (int i = 0; i < 24; ++i) {
            const float x = hv[i];
#pragma unroll
            for (int h = 0; h < 6; ++h) za[h] += x * Wl[(h * 24 + i) * N + term];
        }
        float* zr = z_out + (size_t)r * NF + term * 6;
#pragma unroll
        for (int h = 0; h < 6; ++h) {
            float z = tanhf(za[h]);
            zr[h] = z;
            s6[h] += z;
            q6[h] += z * z;
        }
    }
#pragma unroll
    for (int h = 0; h < 6; ++h) {
        ps[grp * NF + term * 6 + h] = s6[h];
        pq[grp * NF + term * 6 + h] = q6[h];
    }
    __syncthreads();
    for (int f = tid; f < NF; f += 256) {
        float s = 0.f, q = 0.f;
        for (int g2 = 0; g2 < NG; ++g2) { s += ps[g2 * NF + f]; q += pq[g2 * NF + f]; }
        atomicAdd(&stats_out[f], s);
        atomicAdd(&stats_out[NF + f], q);
    }
}

// ---------------------------------------------------------------------------
// Fused final stage: one block, 1024 threads, 4 rows/thread.
// Pass 1: h = BN(z3), aux col 84, f = tanh(h@final_W^T+b), stats(f) in regs.
// Reduce stats (shuffle + LDS). Pass 2: recompute f, fbn-normalize, col 85.
// ---------------------------------------------------------------------------
__global__ __launch_bounds__(1024) void final_fused(
    const float* __restrict__ z3, const float* __restrict__ st3,
    const float* __restrict__ bn_gamma, const float* __restrict__ bn_beta,
    const float* __restrict__ aux1_W, const float* __restrict__ aux1_b,
    const float* __restrict__ aux2_W, const float* __restrict__ aux2_b,
    const float* __restrict__ final_W, const float* __restrict__ final_b,
    const float* __restrict__ fbn_gamma, const float* __restrict__ fbn_beta,
    const float* __restrict__ faux_W, const float* __restrict__ faux_b,
    const float* __restrict__ fout_W, const float* __restrict__ fout_b,
    float* __restrict__ out)
{
    __shared__ float wred[16][12];
    __shared__ float fstat[12];
    const int tid = threadIdx.x;
    const float invB = 1.0f / BATCH;
    float a[6], c[6], fw[36], fbv[6];
#pragma unroll
    for (int j = 0; j < 6; ++j) {
        float s = st3[j], q = st3[6 + j];
        float mu = s * invB, var = q * invB - mu * mu;
        float rstd = rsqrtf(var + EPSV);
        a[j] = rstd * bn_gamma[84 * 6 + j];
        c[j] = bn_beta[84 * 6 + j] - mu * a[j];
        fbv[j] = final_b[j];
    }
#pragma unroll
    for (int j = 0; j < 36; ++j) fw[j] = final_W[j];

    float s6[6], q6[6];
#pragma unroll
    for (int j = 0; j < 6; ++j) { s6[j] = 0.f; q6[j] = 0.f; }

    for (int i = 0; i < 4; ++i) {
        const int r = i * 1024 + tid;
        float h[6];
#pragma unroll
        for (int j = 0; j < 6; ++j) h[j] = z3[(size_t)r * 6 + j] * a[j] + c[j];
        float acc = aux1_b[84];
#pragma unroll
        for (int j = 0; j < 6; ++j) acc += h[j] * aux1_W[84 * 6 + j];
        out[(size_t)r * 86 + 84] = tanhf(acc) * aux2_W[84] + aux2_b[84];
#pragma unroll
        for (int j = 0; j < 6; ++j) {
            float s = fbv[j];
#pragma unroll
            for (int k = 0; k < 6; ++k) s += h[k] * fw[j * 6 + k];
            float f = tanhf(s);
            s6[j] += f; q6[j] += f * f;
        }
    }
    // wave reduce (64 lanes)
#pragma unroll
    for (int off = 32; off >= 1; off >>= 1) {
#pragma unroll
        for (int j = 0; j < 6; ++j) {
            s6[j] += __shfl_xor(s6[j], off, 64);
            q6[j] += __shfl_xor(q6[j], off, 64);
        }
    }
    const int wv = tid >> 6, ln = tid & 63;
    if (ln == 0) {
#pragma unroll
        for (int j = 0; j < 6; ++j) { wred[wv][j] = s6[j]; wred[wv][6 + j] = q6[j]; }
    }
    __syncthreads();
    if (tid < 12) {
        float s = 0.f;
#pragma unroll
        for (int w = 0; w < 16; ++w) s += wred[w][tid];
        fstat[tid] = s;
    }
    __syncthreads();
    float av[6], cv[6];
#pragma unroll
    for (int j = 0; j < 6; ++j) {
        float mu = fstat[j] * invB, var = fstat[6 + j] * invB - mu * mu;
        float rstd = rsqrtf(var + EPSV);
        av[j] = rstd * fbn_gamma[j];
        cv[j] = fbn_beta[j] - mu * av[j];
    }
    const float fxb0 = faux_b[0], foW0 = fout_W[0], fob0 = fout_b[0];
    for (int i = 0; i < 4; ++i) {
        const int r = i * 1024 + tid;
        float h[6];
#pragma unroll
        for (int j = 0; j < 6; ++j) h[j] = z3[(size_t)r * 6 + j] * a[j] + c[j];
        float acc2 = fxb0;
#pragma unroll
        for (int j = 0; j < 6; ++j) {
            float s = fbv[j];
#pragma unroll
            for (int k = 0; k < 6; ++k) s += h[k] * fw[j * 6 + k];
            float fn = tanhf(s) * av[j] + cv[j];
            acc2 += fn * faux_W[j];
        }
        float fa  = tanhf(acc2);
        float pre = fa * foW0 + fob0;
        out[(size_t)r * 86 + 85] = 1.0f / (1.0f + expf(-pre));
    }
}

// ---------------------------------------------------------------------------
extern "C" void kernel_launch(void* const* d_in, const int* in_sizes, int n_in,
                              void* d_out, int out_size, void* d_ws, size_t ws_size,
                              hipStream_t stream)
{
    const float* x      = (const float*)d_in[0];
    const float* gene_W = (const float*)d_in[1];
    const float* gene_b = (const float*)d_in[2];
    const float* term_W = (const float*)d_in[3];
    const float* term_b = (const float*)d_in[4];
    const float* bn_g   = (const float*)d_in[5];
    const float* bn_b   = (const float*)d_in[6];
    const float* a1W    = (const float*)d_in[7];
    const float* a1b    = (const float*)d_in[8];
    const float* a2W    = (const float*)d_in[9];
    const float* a2b    = (const float*)d_in[10];
    const float* fW     = (const float*)d_in[11];
    const float* fb     = (const float*)d_in[12];
    const float* fbn_g  = (const float*)d_in[13];
    const float* fbn_b  = (const float*)d_in[14];
    const float* fxW    = (const float*)d_in[15];
    const float* fxb    = (const float*)d_in[16];
    const float* foW    = (const float*)d_in[17];
    const float* fob    = (const float*)d_in[18];
    float* out = (float*)d_out;

    const size_t PART = (size_t)BATCH * NFEAT * 4;    // 25,165,824
    const size_t TAIL = 6291456 + 1572864 + 393216 + 98304 + 4096;
    const int nsplit = (ws_size >= 2 * PART + TAIL) ? 2 : 1;

    char* ws = (char*)d_ws;
    float* p0 = (float*)ws;
    float* p1 = (float*)(ws + PART);
    char* base = ws + (size_t)nsplit * PART;
    float* z0 = (float*)(base);
    float* z1 = (float*)(base + 6291456);
    float* z2 = (float*)(base + 6291456 + 1572864);
    float* z3 = (float*)(base + 6291456 + 1572864 + 393216);
    float* stats = (float*)(base + 6291456 + 1572864 + 393216 + 98304);
    float* st0 = stats;         // 384 sum + 384 sq
    float* st1 = stats + 768;   // 96+96
    float* st2 = stats + 960;   // 24+24
    float* st3 = stats + 1008;  // 6+6

    hipMemsetAsync(stats, 0, 1020 * sizeof(float), stream);
    gemm_bt<<<dim3(12, 32, nsplit), 256, 0, stream>>>(x, gene_W, gene_b, p0, GDIM / nsplit);
    if (nsplit == 2)
        level_kernel<64, 16, false, 0, 0, true><<<256, 256, 0, stream>>>(
            p0, p1, z0, nullptr, st0, term_W, term_b, bn_g, bn_b, a1W, a1b, a2W, a2b, out);
    else
        level_kernel<64, 16, false, 0, 0, false><<<256, 256, 0, stream>>>(
            p0, nullptr, z0, nullptr, st0, term_W, term_b, bn_g, bn_b, a1W, a1b, a2W, a2b, out);
    level_kernel<16, 16, true, 64, 0, false><<<256, 256, 0, stream>>>(
        z0, nullptr, z1, st0, st1, term_W, term_b, bn_g, bn_b, a1W, a1b, a2W, a2b, out);
    level_kernel<4, 64, true, 80, 64, false><<<64, 256, 0, stream>>>(
        z1, nullptr, z2, st1, st2, term_W, term_b, bn_g, bn_b, a1W, a1b, a2W, a2b, out);
    level_kernel<1, 256, true, 84, 80, false><<<16, 256, 0, stream>>>(
        z2, nullptr, z3, st2, st3, term_W, term_b, bn_g, bn_b, a1W, a1b, a2W, a2b, out);
    final_fused<<<1, 1024, 0, stream>>>(
        z3, st3, bn_g, bn_b, a1W, a1b, a2W, a2b, fW, fb,
        fbn_g, fbn_b, fxW, fxb, foW, fob, out);
}

// Round 4
// 287.568 us; speedup vs baseline: 1.3078x; 1.0921x over previous
//
#include <hip/hip_runtime.h>
#include <stdint.h>
#include <math.h>

#define EPSV   1e-5f
#define BATCH  4096
#define GDIM   4096
#define NFEAT  1536   // 64 terms * 24

typedef __attribute__((ext_vector_type(8))) short bf16x8;
typedef __attribute__((ext_vector_type(4))) float f32x4;
typedef __attribute__((ext_vector_type(4))) uint32_t u32x4;

// pack two f32 -> two bf16 (round-half-up) in one dword
__device__ __forceinline__ uint32_t pkbf(float x, float y) {
    uint32_t a = __float_as_uint(x) + 0x8000u;
    uint32_t b = __float_as_uint(y) + 0x8000u;
    return __builtin_amdgcn_perm(b, a, 0x07060302u);
}
__device__ __forceinline__ uint16_t f2bf(float f) {
    return (uint16_t)((__float_as_uint(f) + 0x8000u) >> 16);
}
// async global->LDS DMA, 16 bytes per lane
__device__ __forceinline__ void glds16(const uint16_t* g, short* l) {
    __builtin_amdgcn_global_load_lds(
        (const __attribute__((address_space(1))) void*)g,
        (__attribute__((address_space(3))) void*)l, 16, 0, 0);
}

// ---------------------------------------------------------------------------
// Convert x (4096x4096) and gene_W (1536x4096) f32 -> bf16. 8 f32/thread.
// ---------------------------------------------------------------------------
__global__ __launch_bounds__(256) void cvt_bf16(
    const float* __restrict__ x, const float* __restrict__ w,
    uint16_t* __restrict__ xb, uint16_t* __restrict__ wb)
{
    const size_t NX = (size_t)BATCH * GDIM / 8;   // 2097152 chunks
    size_t i = (size_t)blockIdx.x * 256 + threadIdx.x;
    const float* src; uint16_t* dst;
    if (i < NX) { src = x + i * 8; dst = xb + i * 8; }
    else        { size_t j = i - NX; src = w + j * 8; dst = wb + j * 8; }
    f32x4 v0 = *(const f32x4*)src;
    f32x4 v1 = *(const f32x4*)(src + 4);
    u32x4 p = (u32x4){pkbf(v0[0],v0[1]), pkbf(v0[2],v0[3]),
                      pkbf(v1[0],v1[1]), pkbf(v1[2],v1[3])};
    *(u32x4*)dst = p;
}

// ---------------------------------------------------------------------------
// m97-style GEMM on bf16 inputs: global_load_lds(16B) staging, 2-barrier
// K-loop. 128x128 tile, BK=32, 4 waves (2x2), wave 64x64 via 4x4 mfma
// 16x16x32. Split-K over z: z=0 -> f32 C0 (+bias); z=1 -> bf16 C1.
// ---------------------------------------------------------------------------
__global__ __launch_bounds__(256) void gemm_glds(
    const uint16_t* __restrict__ A, const uint16_t* __restrict__ Bw,
    const float* __restrict__ bias, float* __restrict__ C0,
    uint16_t* __restrict__ C1, int KC)
{
    const int N = NFEAT, K = GDIM;
    __shared__ short sA[128 * 32];
    __shared__ short sB[128 * 32];
    const int tid  = threadIdx.x;
    const int m0   = blockIdx.y * 128, n0 = blockIdx.x * 128;
    const int kbase = blockIdx.z * KC;
    const int wave = tid >> 6, lane = tid & 63;
    const int wm   = (wave & 1) << 6, wn = (wave >> 1) << 6;
    const int lm   = lane & 15, quad = lane >> 4;

    f32x4 acc[4][4];
#pragma unroll
    for (int i = 0; i < 4; ++i)
#pragma unroll
        for (int j = 0; j < 4; ++j) acc[i][j] = (f32x4){0.f, 0.f, 0.f, 0.f};

    const int r0  = tid >> 2;            // row 0..63 (+64 for second issue)
    const int c0e = (tid & 3) << 3;      // elem col 0/8/16/24
    const uint16_t* gA = A  + (size_t)(m0 + r0) * K + kbase + c0e;
    const uint16_t* gB = Bw + (size_t)(n0 + r0) * K + kbase + c0e;
    short* la0 = &sA[tid * 8];
    short* la1 = &sA[2048 + tid * 8];
    short* lb0 = &sB[tid * 8];
    short* lb1 = &sB[2048 + tid * 8];
    const size_t rowskip = (size_t)64 * K;

    for (int k0 = 0; k0 < KC; k0 += 32) {
        __syncthreads();                 // frag reads of prev iter done
        glds16(gA + k0,            la0);
        glds16(gA + rowskip + k0,  la1);
        glds16(gB + k0,            lb0);
        glds16(gB + rowskip + k0,  lb1);
        __syncthreads();                 // drains vmcnt(0): LDS tiles ready
        bf16x8 af[4], bfr[4];
#pragma unroll
        for (int m = 0; m < 4; ++m)
            af[m]  = *(const bf16x8*)&sA[(wm + m * 16 + lm) * 32 + quad * 8];
#pragma unroll
        for (int n = 0; n < 4; ++n)
            bfr[n] = *(const bf16x8*)&sB[(wn + n * 16 + lm) * 32 + quad * 8];
#pragma unroll
        for (int m = 0; m < 4; ++m)
#pragma unroll
            for (int n = 0; n < 4; ++n)
                acc[m][n] = __builtin_amdgcn_mfma_f32_16x16x32_bf16(
                    af[m], bfr[n], acc[m][n], 0, 0, 0);
    }
    // C/D layout: col = lane&15, row = quad*4 + reg
    if (blockIdx.z == 0) {
#pragma unroll
        for (int n = 0; n < 4; ++n) {
            const int col = n0 + wn + n * 16 + lm;
            const float bv = bias[col];
#pragma unroll
            for (int m = 0; m < 4; ++m) {
                const int row = m0 + wm + m * 16 + (quad << 2);
                float* cp = C0 + (size_t)row * N + col;
#pragma unroll
                for (int r = 0; r < 4; ++r) cp[(size_t)r * N] = acc[m][n][r] + bv;
            }
        }
    } else {
#pragma unroll
        for (int n = 0; n < 4; ++n) {
            const int col = n0 + wn + n * 16 + lm;
#pragma unroll
            for (int m = 0; m < 4; ++m) {
                const int row = m0 + wm + m * 16 + (quad << 2);
                uint16_t* cp = C1 + (size_t)row * N + col;
#pragma unroll
                for (int r = 0; r < 4; ++r) cp[(size_t)r * N] = f2bf(acc[m][n][r]);
            }
        }
    }
}

// ---------------------------------------------------------------------------
// Legacy f32-staging GEMM (fallback plans). Split-K over z, f32 partials.
// ---------------------------------------------------------------------------
__global__ __launch_bounds__(256) void gemm_bt(
    const float* __restrict__ A, const float* __restrict__ Bw,
    const float* __restrict__ bias, float* __restrict__ C, int KC)
{
    const int N = NFEAT, K = GDIM;
    __shared__ short sA[128 * 32];
    __shared__ short sB[128 * 32];
    const int tid  = threadIdx.x;
    const int m0   = blockIdx.y * 128, n0 = blockIdx.x * 128;
    const int kbase = blockIdx.z * KC;
    float* Cp = C + (size_t)blockIdx.z * ((size_t)BATCH * NFEAT);
    const int wave = tid >> 6, lane = tid & 63;
    const int wm   = (wave & 1) << 6, wn = (wave >> 1) << 6;
    const int lm   = lane & 15, quad = lane >> 4;

    f32x4 acc[4][4];
#pragma unroll
    for (int i = 0; i < 4; ++i)
#pragma unroll
        for (int j = 0; j < 4; ++j) acc[i][j] = (f32x4){0.f, 0.f, 0.f, 0.f};

    const int r0 = tid >> 2;
    const int c0 = (tid & 3) << 3;
    const float* ga = A  + (size_t)(m0 + r0) * K + kbase + c0;
    const float* gb = Bw + (size_t)(n0 + r0) * K + kbase + c0;
    uint32_t* wa = (uint32_t*)&sA[r0 * 32 + c0];
    uint32_t* wb = (uint32_t*)&sB[r0 * 32 + c0];
    const size_t rowskip = (size_t)64 * K;

    for (int k0 = 0; k0 < KC; k0 += 32) {
        f32x4 a00 = *(const f32x4*)(ga + k0);
        f32x4 a01 = *(const f32x4*)(ga + k0 + 4);
        f32x4 a10 = *(const f32x4*)(ga + rowskip + k0);
        f32x4 a11 = *(const f32x4*)(ga + rowskip + k0 + 4);
        f32x4 b00 = *(const f32x4*)(gb + k0);
        f32x4 b01 = *(const f32x4*)(gb + k0 + 4);
        f32x4 b10 = *(const f32x4*)(gb + rowskip + k0);
        f32x4 b11 = *(const f32x4*)(gb + rowskip + k0 + 4);
        u32x4 pa0 = (u32x4){pkbf(a00[0],a00[1]), pkbf(a00[2],a00[3]),
                            pkbf(a01[0],a01[1]), pkbf(a01[2],a01[3])};
        u32x4 pa1 = (u32x4){pkbf(a10[0],a10[1]), pkbf(a10[2],a10[3]),
                            pkbf(a11[0],a11[1]), pkbf(a11[2],a11[3])};
        u32x4 pb0 = (u32x4){pkbf(b00[0],b00[1]), pkbf(b00[2],b00[3]),
                            pkbf(b01[0],b01[1]), pkbf(b01[2],b01[3])};
        u32x4 pb1 = (u32x4){pkbf(b10[0],b10[1]), pkbf(b10[2],b10[3]),
                            pkbf(b11[0],b11[1]), pkbf(b11[2],b11[3])};
        __syncthreads();
        *(u32x4*)wa               = pa0;
        *(u32x4*)(wa + 64*32/2)   = pa1;
        *(u32x4*)wb               = pb0;
        *(u32x4*)(wb + 64*32/2)   = pb1;
        __syncthreads();
        bf16x8 af[4], bfr[4];
#pragma unroll
        for (int m = 0; m < 4; ++m)
            af[m]  = *(const bf16x8*)&sA[(wm + m * 16 + lm) * 32 + quad * 8];
#pragma unroll
        for (int n = 0; n < 4; ++n)
            bfr[n] = *(const bf16x8*)&sB[(wn + n * 16 + lm) * 32 + quad * 8];
#pragma unroll
        for (int m = 0; m < 4; ++m)
#pragma unroll
            for (int n = 0; n < 4; ++n)
                acc[m][n] = __builtin_amdgcn_mfma_f32_16x16x32_bf16(
                    af[m], bfr[n], acc[m][n], 0, 0, 0);
    }
#pragma unroll
    for (int n = 0; n < 4; ++n) {
        const int col = n0 + wn + n * 16 + lm;
        const float bv = (blockIdx.z == 0) ? bias[col] : 0.f;
#pragma unroll
        for (int m = 0; m < 4; ++m) {
            const int row = m0 + wm + m * 16 + (quad << 2);
            float* cp = Cp + (size_t)row * N + col;
#pragma unroll
            for (int r = 0; r < 4; ++r) cp[(size_t)r * N] = acc[m][n][r] + bv;
        }
    }
}

// ---------------------------------------------------------------------------
// Level kernel. IN2MODE: 0 = single input, 1 = +f32 partial, 2 = +bf16 partial.
// ---------------------------------------------------------------------------
template <int N, int ROWS, bool HAS_PREV, int OFF, int PREV_OFF, int IN2MODE>
__global__ __launch_bounds__(256) void level_kernel(
    const float* __restrict__ in, const void* __restrict__ in2,
    float* __restrict__ z_out,
    const float* __restrict__ stats_prev, float* __restrict__ stats_out,
    const float* __restrict__ term_W, const float* __restrict__ term_b,
    const float* __restrict__ bn_gamma, const float* __restrict__ bn_beta,
    const float* __restrict__ aux1_W, const float* __restrict__ aux1_b,
    const float* __restrict__ aux2_W, const float* __restrict__ aux2_b,
    float* __restrict__ out)
{
    constexpr int IN_W  = 24 * N;
    constexpr int NF    = 6 * N;
    constexpr int NG    = 256 / N;
    constexpr int ITERS = (ROWS * N) / 256;
    constexpr int NPREV = HAS_PREV ? 4 * N : 1;

    __shared__ float Wl[144 * N];
    __shared__ float tbl[6 * N];
    __shared__ float aA[HAS_PREV ? IN_W : 1];
    __shared__ float aC[HAS_PREV ? IN_W : 1];
    __shared__ float a1wL[HAS_PREV ? 6 * NPREV : 1];
    __shared__ float a1bL[NPREV], a2wL[NPREV], a2bL[NPREV];
    __shared__ float ps[NG * NF], pq[NG * NF];

    const int tid = threadIdx.x;
    for (int idx = tid; idx < 144 * N; idx += 256) {
        int t = idx / 144, fh = idx - t * 144;
        Wl[fh * N + t] = term_W[(OFF + t) * 144 + fh];
    }
    for (int idx = tid; idx < 6 * N; idx += 256) {
        int t = idx / 6, h = idx - t * 6;
        tbl[h * N + t] = term_b[(OFF + t) * 6 + h];
    }
    if constexpr (HAS_PREV) {
        const float invB = 1.0f / BATCH;
        for (int j = tid; j < IN_W; j += 256) {
            float s = stats_prev[j], q = stats_prev[IN_W + j];
            float mu = s * invB;
            float var = q * invB - mu * mu;
            float rstd = rsqrtf(var + EPSV);
            float a = rstd * bn_gamma[PREV_OFF * 6 + j];
            int t = j / 24, i = j - t * 24;
            aA[i * N + t] = a;
            aC[i * N + t] = bn_beta[PREV_OFF * 6 + j] - mu * a;
        }
        for (int idx = tid; idx < 6 * NPREV; idx += 256) {
            int t = idx / 6, h = idx - t * 6;
            a1wL[h * NPREV + t] = aux1_W[(PREV_OFF + t) * 6 + h];
        }
        for (int t = tid; t < NPREV; t += 256) {
            a1bL[t] = aux1_b[PREV_OFF + t];
            a2wL[t] = aux2_W[PREV_OFF + t];
            a2bL[t] = aux2_b[PREV_OFF + t];
        }
    }
    __syncthreads();

    const int term = tid & (N - 1);
    const int grp  = tid / N;
    float s6[6], q6[6];
#pragma unroll
    for (int h = 0; h < 6; ++h) { s6[h] = 0.f; q6[h] = 0.f; }

    for (int it = 0; it < ITERS; ++it) {
        const int r = blockIdx.x * ROWS + it * NG + grp;
        const float* inrow = in + (size_t)r * IN_W + term * 24;
        float hv[24];
#pragma unroll
        for (int i4 = 0; i4 < 6; ++i4) {
            f32x4 v = *(const f32x4*)(inrow + 4 * i4);
            hv[4*i4+0] = v[0]; hv[4*i4+1] = v[1];
            hv[4*i4+2] = v[2]; hv[4*i4+3] = v[3];
        }
        if constexpr (IN2MODE == 1) {
            const float* inrow2 = (const float*)in2 + (size_t)r * IN_W + term * 24;
#pragma unroll
            for (int i4 = 0; i4 < 6; ++i4) {
                f32x4 v = *(const f32x4*)(inrow2 + 4 * i4);
                hv[4*i4+0] += v[0]; hv[4*i4+1] += v[1];
                hv[4*i4+2] += v[2]; hv[4*i4+3] += v[3];
            }
        } else if constexpr (IN2MODE == 2) {
            const uint32_t* p2 = (const uint32_t*)((const uint16_t*)in2 +
                                 (size_t)r * IN_W + term * 24);
#pragma unroll
            for (int i = 0; i < 12; ++i) {
                uint32_t u = p2[i];
                hv[2*i]   += __uint_as_float(u << 16);
                hv[2*i+1] += __uint_as_float(u & 0xffff0000u);
            }
        }
        if constexpr (HAS_PREV) {
#pragma unroll
            for (int i = 0; i < 24; ++i)
                hv[i] = hv[i] * aA[i * N + term] + aC[i * N + term];
#pragma unroll
            for (int s = 0; s < 4; ++s) {
                const int tp = term * 4 + s;
                float acc = a1bL[tp];
#pragma unroll
                for (int h2 = 0; h2 < 6; ++h2) acc += hv[s * 6 + h2] * a1wL[h2 * NPREV + tp];
                float a1 = tanhf(acc);
                out[(size_t)r * 86 + PREV_OFF + tp] = a1 * a2wL[tp] + a2bL[tp];
            }
        }
        float za[6];
#pragma unroll
        for (int h = 0; h < 6; ++h) za[h] = tbl[h * N + term];
#pragma unroll
        for (int i = 0; i < 24; ++i) {
            const float x = hv[i];
#pragma unroll
            for (int h = 0; h < 6; ++h) za[h] += x * Wl[(h * 24 + i) * N + term];
        }
        float* zr = z_out + (size_t)r * NF + term * 6;
#pragma unroll
        for (int h = 0; h < 6; ++h) {
            float z = tanhf(za[h]);
            zr[h] = z;
            s6[h] += z;
            q6[h] += z * z;
        }
    }
#pragma unroll
    for (int h = 0; h < 6; ++h) {
        ps[grp * NF + term * 6 + h] = s6[h];
        pq[grp * NF + term * 6 + h] = q6[h];
    }
    __syncthreads();
    for (int f = tid; f < NF; f += 256) {
        float s = 0.f, q = 0.f;
        for (int g2 = 0; g2 < NG; ++g2) { s += ps[g2 * NF + f]; q += pq[g2 * NF + f]; }
        atomicAdd(&stats_out[f], s);
        atomicAdd(&stats_out[NF + f], q);
    }
}

// ---------------------------------------------------------------------------
// Fused final stage: one block, 1024 threads, 4 rows/thread. (See R2 notes.)
// ---------------------------------------------------------------------------
__global__ __launch_bounds__(1024) void final_fused(
    const float* __restrict__ z3, const float* __restrict__ st3,
    const float* __restrict__ bn_gamma, const float* __restrict__ bn_beta,
    const float* __restrict__ aux1_W, const float* __restrict__ aux1_b,
    const float* __restrict__ aux2_W, const float* __restrict__ aux2_b,
    const float* __restrict__ final_W, const float* __restrict__ final_b,
    const float* __restrict__ fbn_gamma, const float* __restrict__ fbn_beta,
    const float* __restrict__ faux_W, const float* __restrict__ faux_b,
    const float* __restrict__ fout_W, const float* __restrict__ fout_b,
    float* __restrict__ out)
{
    __shared__ float wred[16][12];
    __shared__ float fstat[12];
    const int tid = threadIdx.x;
    const float invB = 1.0f / BATCH;
    float a[6], c[6], fw[36], fbv[6];
#pragma unroll
    for (int j = 0; j < 6; ++j) {
        float s = st3[j], q = st3[6 + j];
        float mu = s * invB, var = q * invB - mu * mu;
        float rstd = rsqrtf(var + EPSV);
        a[j] = rstd * bn_gamma[84 * 6 + j];
        c[j] = bn_beta[84 * 6 + j] - mu * a[j];
        fbv[j] = final_b[j];
    }
#pragma unroll
    for (int j = 0; j < 36; ++j) fw[j] = final_W[j];

    float s6[6], q6[6];
#pragma unroll
    for (int j = 0; j < 6; ++j) { s6[j] = 0.f; q6[j] = 0.f; }

    for (int i = 0; i < 4; ++i) {
        const int r = i * 1024 + tid;
        float h[6];
#pragma unroll
        for (int j = 0; j < 6; ++j) h[j] = z3[(size_t)r * 6 + j] * a[j] + c[j];
        float acc = aux1_b[84];
#pragma unroll
        for (int j = 0; j < 6; ++j) acc += h[j] * aux1_W[84 * 6 + j];
        out[(size_t)r * 86 + 84] = tanhf(acc) * aux2_W[84] + aux2_b[84];
#pragma unroll
        for (int j = 0; j < 6; ++j) {
            float s = fbv[j];
#pragma unroll
            for (int k = 0; k < 6; ++k) s += h[k] * fw[j * 6 + k];
            float f = tanhf(s);
            s6[j] += f; q6[j] += f * f;
        }
    }
#pragma unroll
    for (int off = 32; off >= 1; off >>= 1) {
#pragma unroll
        for (int j = 0; j < 6; ++j) {
            s6[j] += __shfl_xor(s6[j], off, 64);
            q6[j] += __shfl_xor(q6[j], off, 64);
        }
    }
    const int wv = tid >> 6, ln = tid & 63;
    if (ln == 0) {
#pragma unroll
        for (int j = 0; j < 6; ++j) { wred[wv][j] = s6[j]; wred[wv][6 + j] = q6[j]; }
    }
    __syncthreads();
    if (tid < 12) {
        float s = 0.f;
#pragma unroll
        for (int w = 0; w < 16; ++w) s += wred[w][tid];
        fstat[tid] = s;
    }
    __syncthreads();
    float av[6], cv[6];
#pragma unroll
    for (int j = 0; j < 6; ++j) {
        float mu = fstat[j] * invB, var = fstat[6 + j] * invB - mu * mu;
        float rstd = rsqrtf(var + EPSV);
        av[j] = rstd * fbn_gamma[j];
        cv[j] = fbn_beta[j] - mu * av[j];
    }
    const float fxb0 = faux_b[0], foW0 = fout_W[0], fob0 = fout_b[0];
    for (int i = 0; i < 4; ++i) {
        const int r = i * 1024 + tid;
        float h[6];
#pragma unroll
        for (int j = 0; j < 6; ++j) h[j] = z3[(size_t)r * 6 + j] * a[j] + c[j];
        float acc2 = fxb0;
#pragma unroll
        for (int j = 0; j < 6; ++j) {
            float s = fbv[j];
#pragma unroll
            for (int k = 0; k < 6; ++k) s += h[k] * fw[j * 6 + k];
            float fn = tanhf(s) * av[j] + cv[j];
            acc2 += fn * faux_W[j];
        }
        float fa  = tanhf(acc2);
        float pre = fa * foW0 + fob0;
        out[(size_t)r * 86 + 85] = 1.0f / (1.0f + expf(-pre));
    }
}

// ---------------------------------------------------------------------------
extern "C" void kernel_launch(void* const* d_in, const int* in_sizes, int n_in,
                              void* d_out, int out_size, void* d_ws, size_t ws_size,
                              hipStream_t stream)
{
    const float* x      = (const float*)d_in[0];
    const float* gene_W = (const float*)d_in[1];
    const float* gene_b = (const float*)d_in[2];
    const float* term_W = (const float*)d_in[3];
    const float* term_b = (const float*)d_in[4];
    const float* bn_g   = (const float*)d_in[5];
    const float* bn_b   = (const float*)d_in[6];
    const float* a1W    = (const float*)d_in[7];
    const float* a1b    = (const float*)d_in[8];
    const float* a2W    = (const float*)d_in[9];
    const float* a2b    = (const float*)d_in[10];
    const float* fW     = (const float*)d_in[11];
    const float* fb     = (const float*)d_in[12];
    const float* fbn_g  = (const float*)d_in[13];
    const float* fbn_b  = (const float*)d_in[14];
    const float* fxW    = (const float*)d_in[15];
    const float* fxb    = (const float*)d_in[16];
    const float* foW    = (const float*)d_in[17];
    const float* fob    = (const float*)d_in[18];
    float* out = (float*)d_out;

    const size_t PART = 25165824;                 // f32 partial (4096x1536)
    const size_t XB   = 33554432;                 // x bf16
    const size_t WBS  = 12582912;                 // gene_W bf16
    const size_t P1B  = 12582912;                 // bf16 partial
    const size_t TAILSZ = 6291456 + 1572864 + 393216 + 98304 + 4096;
    const size_t needA = XB + WBS + PART + P1B + TAILSZ;   // 92.2 MB
    const size_t needB = 2 * PART + TAILSZ;                // 58.7 MB
    const int plan = (ws_size >= needA) ? 0 : ((ws_size >= needB) ? 1 : 2);

    char* ws = (char*)d_ws;
    char* base;
    uint16_t *xbuf = nullptr, *wbuf = nullptr, *p1b = nullptr;
    float *p0, *p1f = nullptr;
    if (plan == 0) {
        xbuf = (uint16_t*)ws;
        wbuf = (uint16_t*)(ws + XB);
        p0   = (float*)(ws + XB + WBS);
        p1b  = (uint16_t*)(ws + XB + WBS + PART);
        base = ws + XB + WBS + PART + P1B;
    } else if (plan == 1) {
        p0   = (float*)ws;
        p1f  = (float*)(ws + PART);
        base = ws + 2 * PART;
    } else {
        p0   = (float*)ws;
        base = ws + PART;
    }
    float* z0 = (float*)(base);
    float* z1 = (float*)(base + 6291456);
    float* z2 = (float*)(base + 6291456 + 1572864);
    float* z3 = (float*)(base + 6291456 + 1572864 + 393216);
    float* stats = (float*)(base + 6291456 + 1572864 + 393216 + 98304);
    float* st0 = stats;
    float* st1 = stats + 768;
    float* st2 = stats + 960;
    float* st3 = stats + 1008;

    hipMemsetAsync(stats, 0, 1020 * sizeof(float), stream);
    if (plan == 0) {
        cvt_bf16<<<11264, 256, 0, stream>>>(x, gene_W, xbuf, wbuf);
        gemm_glds<<<dim3(12, 32, 2), 256, 0, stream>>>(xbuf, wbuf, gene_b, p0, p1b, GDIM / 2);
        level_kernel<64, 16, false, 0, 0, 2><<<256, 256, 0, stream>>>(
            p0, p1b, z0, nullptr, st0, term_W, term_b, bn_g, bn_b, a1W, a1b, a2W, a2b, out);
    } else if (plan == 1) {
        gemm_bt<<<dim3(12, 32, 2), 256, 0, stream>>>(x, gene_W, gene_b, p0, GDIM / 2);
        level_kernel<64, 16, false, 0, 0, 1><<<256, 256, 0, stream>>>(
            p0, p1f, z0, nullptr, st0, term_W, term_b, bn_g, bn_b, a1W, a1b, a2W, a2b, out);
    } else {
        gemm_bt<<<dim3(12, 32, 1), 256, 0, stream>>>(x, gene_W, gene_b, p0, GDIM);
        level_kernel<64, 16, false, 0, 0, 0><<<256, 256, 0, stream>>>(
            p0, nullptr, z0, nullptr, st0, term_W, term_b, bn_g, bn_b, a1W, a1b, a2W, a2b, out);
    }
    level_kernel<16, 16, true, 64, 0, 0><<<256, 256, 0, stream>>>(
        z0, nullptr, z1, st0, st1, term_W, term_b, bn_g, bn_b, a1W, a1b, a2W, a2b, out);
    level_kernel<4, 64, true, 80, 64, 0><<<64, 256, 0, stream>>>(
        z1, nullptr, z2, st1, st2, term_W, term_b, bn_g, bn_b, a1W, a1b, a2W, a2b, out);
    level_kernel<1, 256, true, 84, 80, 0><<<16, 256, 0, stream>>>(
        z2, nullptr, z3, st2, st3, term_W, term_b, bn_g, bn_b, a1W, a1b, a2W, a2b, out);
    final_fused<<<1, 1024, 0, stream>>>(
        z3, st3, bn_g, bn_b, a1W, a1b, a2W, a2b, fW, fb,
        fbn_g, fbn_b, fxW, fxb, foW, fob, out);
}